// Round 6
// baseline (427.429 us; speedup 1.0000x reference)
//
#include <hip/hip_runtime.h>
#include <hip/hip_bf16.h>

#define DEVI __device__ __forceinline__

typedef __bf16 bf16x8 __attribute__((ext_vector_type(8)));
typedef __bf16 bf16x4 __attribute__((ext_vector_type(4)));
typedef float f32x4 __attribute__((ext_vector_type(4)));

constexpr int B_ = 4, S_ = 2048, E_ = 1024, H_ = 16, D_ = 64;
constexpr int N_ = B_ * S_;          // 8192 tokens
constexpr float SC2_ = 0.18033688011112042f;  // (1/sqrt(64)) * log2(e)

// ---- workspace layout (bytes) ----
constexpr size_t XB_OFF = 0;           // bf16 [3][N][E]
constexpr size_t WB_OFF = 50331648;    // bf16 [4][E][E]
constexpr size_t QB_OFF = 58720256;    // bf16 [B][H][S][D]
constexpr size_t KB_OFF = 75497472;    // bf16 [B][H][S][D]
constexpr size_t VT_OFF = 92274688;    // bf16 [B][H][D][S]
constexpr size_t CTX_OFF = 109051904;  // bf16 [N][E]
constexpr size_t LS_OFF = 125829120;   // f32  [B][H][S]
constexpr size_t WS_NEED = 126353408;

typedef const __attribute__((address_space(1))) void* gas_ptr;
typedef __attribute__((address_space(3))) void* las_ptr;

DEVI void load_lds16(const void* g, void* l) {
  __builtin_amdgcn_global_load_lds((gas_ptr)g, (las_ptr)l, 16, 0, 0);
}

DEVI f32x4 mfma16(bf16x8 a, bf16x8 b, f32x4 c) {
  return __builtin_amdgcn_mfma_f32_16x16x32_bf16(a, b, c, 0, 0, 0);
}

// xor-swizzle key: 16B slot permutation per row, kills bank-position aliasing
DEVI int swz(int row) { return ((row >> 1) ^ (row >> 3)) & 3; }

#if __has_builtin(__builtin_amdgcn_exp2f)
DEVI float ex2(float x) { return __builtin_amdgcn_exp2f(x); }
#else
DEVI float ex2(float x) { return exp2f(x); }
#endif

// ---------------- conversion fp32 -> bf16 ----------------
__global__ __launch_bounds__(256) void conv_x(const float* __restrict__ q,
                                              const float* __restrict__ k,
                                              const float* __restrict__ v,
                                              __bf16* __restrict__ dst) {
  const float* src = (blockIdx.y == 0) ? q : ((blockIdx.y == 1) ? k : v);
  __bf16* d = dst + (size_t)blockIdx.y * N_ * E_;
  size_t i = ((size_t)blockIdx.x * blockDim.x + threadIdx.x) * 4;
  float4 f = *(const float4*)(src + i);
  bf16x4 o;
  o[0] = (__bf16)f.x; o[1] = (__bf16)f.y; o[2] = (__bf16)f.z; o[3] = (__bf16)f.w;
  *(bf16x4*)(d + i) = o;
}

__global__ __launch_bounds__(256) void conv_w(const float* __restrict__ wq,
                                              const float* __restrict__ wk,
                                              const float* __restrict__ wv,
                                              const float* __restrict__ wo,
                                              __bf16* __restrict__ dst) {
  const float* src = (blockIdx.y == 0) ? wq : ((blockIdx.y == 1) ? wk :
                     ((blockIdx.y == 2) ? wv : wo));
  __bf16* d = dst + (size_t)blockIdx.y * E_ * E_;
  size_t i = ((size_t)blockIdx.x * blockDim.x + threadIdx.x) * 4;
  float4 f = *(const float4*)(src + i);
  bf16x4 o;
  o[0] = (__bf16)f.x; o[1] = (__bf16)f.y; o[2] = (__bf16)f.z; o[3] = (__bf16)f.w;
  *(bf16x4*)(d + i) = o;
}

// ---------------- fused QKV projection GEMM ----------------
__global__ __launch_bounds__(256) void gemm_qkv(const __bf16* __restrict__ Xb,
                                                const __bf16* __restrict__ Wb,
                                                const float* __restrict__ bq,
                                                const float* __restrict__ bk,
                                                const float* __restrict__ bv,
                                                __bf16* __restrict__ Qb,
                                                __bf16* __restrict__ Kb,
                                                __bf16* __restrict__ Vt) {
  __shared__ __attribute__((aligned(16))) __bf16 As[128 * 32];
  __shared__ __attribute__((aligned(16))) __bf16 Bs[128 * 32];
  const int z = blockIdx.z;
  const __bf16* A = Xb + (size_t)z * N_ * E_;
  const __bf16* W = Wb + (size_t)z * E_ * E_;
  const float* bias = (z == 0) ? bq : ((z == 1) ? bk : bv);
  const int m0 = blockIdx.x * 128, n0 = blockIdx.y * 128;
  const int t = threadIdx.x, lane = t & 63, w = t >> 6;
  const int wm = w >> 1, wn = w & 1;
  const int l15 = lane & 15, g = lane >> 4;

  f32x4 acc[4][4] = {};

  for (int kk = 0; kk < E_; kk += 32) {
#pragma unroll
    for (int i = 0; i < 2; ++i) {
      int c = t + i * 256;
      int row = c >> 2, kc = c & 3;
      int sl = kc ^ swz(row);
      load_lds16(A + (size_t)(m0 + row) * E_ + kk + sl * 8, (void*)(As + c * 8));
      load_lds16(W + (size_t)(n0 + row) * E_ + kk + sl * 8, (void*)(Bs + c * 8));
    }
    __syncthreads();
    bf16x8 a[4], b[4];
#pragma unroll
    for (int i = 0; i < 4; ++i) {
      int row = wm * 64 + i * 16 + l15;
      a[i] = *(const bf16x8*)(As + row * 32 + (g ^ swz(row)) * 8);
    }
#pragma unroll
    for (int j = 0; j < 4; ++j) {
      int row = wn * 64 + j * 16 + l15;
      b[j] = *(const bf16x8*)(Bs + row * 32 + (g ^ swz(row)) * 8);
    }
#pragma unroll
    for (int i = 0; i < 4; ++i)
#pragma unroll
      for (int j = 0; j < 4; ++j)
        acc[i][j] = mfma16(a[i], b[j], acc[i][j]);
    __syncthreads();
  }

#pragma unroll
  for (int i = 0; i < 4; ++i) {
    int mloc = wm * 64 + i * 16 + (g << 2);
#pragma unroll
    for (int j = 0; j < 4; ++j) {
      int nloc = wn * 64 + j * 16 + l15;
      int n = n0 + nloc;
      int h = n >> 6, d = n & 63;
      float bs = bias[n];
      if (z == 2) {
        int m = m0 + mloc;
        int bb = m >> 11, s = m & 2047;
        bf16x4 pk;
#pragma unroll
        for (int r = 0; r < 4; ++r) pk[r] = (__bf16)(acc[i][j][r] + bs);
        *(bf16x4*)(Vt + ((size_t)(bb * H_ + h) * D_ + d) * S_ + s) = pk;
      } else {
        __bf16* dst = (z == 0) ? Qb : Kb;
#pragma unroll
        for (int r = 0; r < 4; ++r) {
          int m = m0 + mloc + r;
          int bb = m >> 11, s = m & 2047;
          dst[((size_t)(bb * H_ + h) * S_ + s) * D_ + d] = (__bf16)(acc[i][j][r] + bs);
        }
      }
    }
  }
}

// ---------------- fused attention via S^T: no P transpose ----------------
// (unchanged — 2-deep counted-vmcnt K/V pipeline)
__global__ __launch_bounds__(256, 4) void attn_pv(const __bf16* __restrict__ Qb,
                                                  const __bf16* __restrict__ Kb,
                                                  const __bf16* __restrict__ Vt,
                                                  float* __restrict__ Lsum,
                                                  __bf16* __restrict__ Ctx) {
  // [buf][ Ks 4096 elems | Vs 4096 elems ] = 2 x 16KB
  __shared__ __attribute__((aligned(16))) __bf16 smem[2][8192];

  const int q0 = blockIdx.x * 128;
  const int bh = blockIdx.y;
  const __bf16* Qh = Qb + (size_t)bh * S_ * D_;
  const __bf16* Kh = Kb + (size_t)bh * S_ * D_;
  const __bf16* Vh = Vt + (size_t)bh * D_ * S_;
  const int t = threadIdx.x, lane = t & 63, w = t >> 6;
  const int l15 = lane & 15, g = lane >> 4;
  // interleaved m->k mapping: k_local = 8*(m>>2) + 4*blk + (m&3)
  const int ksel = 8 * (l15 >> 2) + (l15 & 3);

  // Q fragments loaded directly global->VGPR
  bf16x8 qf[2][2]; // [jb][ks]
#pragma unroll
  for (int jb = 0; jb < 2; ++jb) {
    int row = w * 32 + jb * 16 + l15;
#pragma unroll
    for (int ks = 0; ks < 2; ++ks)
      qf[jb][ks] = *(const bf16x8*)(Qh + (size_t)(q0 + row) * D_ + ks * 32 + g * 8);
  }

  bf16x8 ones;
#pragma unroll
  for (int i = 0; i < 8; ++i) ones[i] = (__bf16)1.0f;

  f32x4 acc[4][2] = {};  // [d-block][jb] — O^T tile
  f32x4 lacc[2] = {};    // denominator via ones-MFMA

  // stage one 64-wide K/V tile (4 loads/thread: 2 K + 2 V)
  auto stage_kv = [&](int kk0, __bf16* buf) {
#pragma unroll
    for (int i = 0; i < 2; ++i) {
      int c = t + i * 256;
      int sub = c >> 8, rem = c & 255, row = rem >> 2, kc = rem & 3;
      int sl = kc ^ swz(row);
      load_lds16(Kh + (size_t)(kk0 + row) * D_ + sub * 32 + sl * 8, (void*)(buf + c * 8));
      load_lds16(Vh + (size_t)row * S_ + kk0 + sub * 32 + sl * 8, (void*)(buf + 4096 + c * 8));
    }
  };

  auto compute = [&](const __bf16* Ksb) {
    const __bf16* Vsb = Ksb + 4096;
#pragma unroll
    for (int chunk = 0; chunk < 2; ++chunk) {
      f32x4 sc[2][2]; // [blk][jb]
#pragma unroll
      for (int blk = 0; blk < 2; ++blk) {
        int krow = chunk * 32 + 4 * blk + ksel;
        int so = (g ^ swz(krow)) * 8;
        bf16x8 kf0 = *(const bf16x8*)(Ksb + krow * 32 + so);
        bf16x8 kf1 = *(const bf16x8*)(Ksb + 2048 + krow * 32 + so);
#pragma unroll
        for (int jb = 0; jb < 2; ++jb) {
          f32x4 s = {};
          s = mfma16(kf0, qf[jb][0], s);
          s = mfma16(kf1, qf[jb][1], s);
          sc[blk][jb] = s;
        }
      }
      bf16x8 pf[2];
#pragma unroll
      for (int jb = 0; jb < 2; ++jb) {
#pragma unroll
        for (int r = 0; r < 4; ++r) {
          pf[jb][r]     = (__bf16)ex2(sc[0][jb][r] * SC2_);
          pf[jb][4 + r] = (__bf16)ex2(sc[1][jb][r] * SC2_);
        }
        lacc[jb] = mfma16(ones, pf[jb], lacc[jb]);
      }
      __builtin_amdgcn_s_setprio(1);
#pragma unroll
      for (int mb = 0; mb < 4; ++mb) {
        int row = mb * 16 + l15;
        bf16x8 vf = *(const bf16x8*)(Vsb + chunk * 2048 + row * 32 + (g ^ swz(row)) * 8);
#pragma unroll
        for (int jb = 0; jb < 2; ++jb)
          acc[mb][jb] = mfma16(vf, pf[jb], acc[mb][jb]);
      }
      __builtin_amdgcn_s_setprio(0);
    }
  };

  // prologue: fill both buffers (tiles 0 and 1)
  stage_kv(0, smem[0]);
  stage_kv(64, smem[1]);

  for (int tt = 0; tt < 30; ++tt) {
    asm volatile("s_waitcnt vmcnt(4)" ::: "memory");
    __builtin_amdgcn_s_barrier();
    compute(smem[tt & 1]);
    __builtin_amdgcn_s_barrier();             // all waves done reading buf
    stage_kv((tt + 2) * 64, smem[tt & 1]);    // issue-only, no wait
  }
  asm volatile("s_waitcnt vmcnt(4)" ::: "memory");
  __builtin_amdgcn_s_barrier();
  compute(smem[0]);
  asm volatile("s_waitcnt vmcnt(0)" ::: "memory");
  __builtin_amdgcn_s_barrier();
  compute(smem[1]);

  // every lane holds l for its own q column in lacc[jb][0]
  if (lane < 16) {
#pragma unroll
    for (int jb = 0; jb < 2; ++jb)
      Lsum[(size_t)bh * S_ + q0 + w * 32 + jb * 16 + lane] = lacc[jb][0];
  }

  const int bb = bh >> 4, h = bh & 15;
#pragma unroll
  for (int jb = 0; jb < 2; ++jb) {
    float invl = 1.0f / lacc[jb][0];
    int q = q0 + w * 32 + jb * 16 + l15;
#pragma unroll
    for (int mb = 0; mb < 4; ++mb) {
      int d = mb * 16 + (g << 2);
      bf16x4 pk;
#pragma unroll
      for (int r = 0; r < 4; ++r) pk[r] = (__bf16)(acc[mb][jb][r] * invl);
      *(bf16x4*)(Ctx + ((size_t)bb * S_ + q) * E_ + h * 64 + d) = pk;
    }
  }
}

// ---------------- fused tail: attn mean + out-proj GEMM ----------------
// v6: round-4 config (waves=3 — known-good, zero spill) + one-head-ahead
// prefetch of Q fragments / Lsum raw value only. The waves=4 occupancy
// experiment is deferred: combined with the prefetch's +~18 live regs it
// was the one risk item in the round-5 submission that failed to bench.

DEVI void attn_mean_body(int id, __bf16* smem,
                         const __bf16* __restrict__ Qb,
                         const __bf16* __restrict__ Kb,
                         const float* __restrict__ Lsum,
                         float* __restrict__ meanout) {
  // smem: two K buffers of 8192 bf16 (16KB each)
  const int k0 = (id & 15) * 128;
  const int q0 = ((id >> 4) & 15) * 128;
  const int bI = id >> 8;
  const int t = threadIdx.x, lane = t & 63, w = t >> 6;
  const int l15 = lane & 15, g = lane >> 4;
  const int ksel = 8 * (l15 >> 2) + (l15 & 3);

  const __bf16* Qbase = Qb + (size_t)bI * H_ * S_ * D_;
  const __bf16* Kbase = Kb + (size_t)bI * H_ * S_ * D_;
  const float* Lbase = Lsum + (size_t)bI * H_ * S_;
  const int qrow0 = q0 + w * 32 + l15;   // jb adds +16

  f32x4 macc[4][2][2] = {}; // [chunk][blk][jb]

  auto stage_k = [&](int h, __bf16* buf) {
    const __bf16* Kh = Kbase + (size_t)h * S_ * D_;
#pragma unroll
    for (int i = 0; i < 4; ++i) {
      int c = t + i * 256;
      int sub = c >> 9, rem = c & 511, row = rem >> 2, kc = rem & 3;
      int sl = kc ^ swz(row);
      load_lds16(Kh + (size_t)(k0 + row) * D_ + sub * 32 + sl * 8, (void*)(buf + c * 8));
    }
  };

  // prologue: stage K[0], prefetch q/l for head 0
  stage_k(0, smem);
  bf16x8 qf[2][2];
  float lraw[2];
#pragma unroll
  for (int jb = 0; jb < 2; ++jb) {
#pragma unroll
    for (int ks = 0; ks < 2; ++ks)
      qf[jb][ks] = *(const bf16x8*)(Qbase + (size_t)(qrow0 + jb * 16) * D_ + ks * 32 + g * 8);
    lraw[jb] = Lbase[qrow0 + jb * 16];
  }

  for (int h = 0; h < H_; ++h) {   // rolled: avoid 16x code bloat / live-range blowup
    __bf16* cur = (h & 1) ? (smem + 8192) : smem;
    __bf16* nxt = (h & 1) ? smem : (smem + 8192);

    // everything issued during head h-1 (K[h] stage, qf, lraw) is >=1 full
    // compute phase old -> this drain is near-free
    asm volatile("s_waitcnt vmcnt(0)" ::: "memory");
    __builtin_amdgcn_s_barrier();

    // prefetch next head's operands; in flight across this compute phase
    bf16x8 qfn[2][2];
    float lrawn[2];
    if (h + 1 < H_) {
      const __bf16* Qn = Qbase + (size_t)(h + 1) * S_ * D_;
#pragma unroll
      for (int jb = 0; jb < 2; ++jb) {
#pragma unroll
        for (int ks = 0; ks < 2; ++ks)
          qfn[jb][ks] = *(const bf16x8*)(Qn + (size_t)(qrow0 + jb * 16) * D_ + ks * 32 + g * 8);
        lrawn[jb] = Lbase[(size_t)(h + 1) * S_ + qrow0 + jb * 16];
      }
      stage_k(h + 1, nxt);
    }
    __builtin_amdgcn_sched_barrier(0);  // pin: prefetch issued before compute

    float invl[2];
#pragma unroll
    for (int jb = 0; jb < 2; ++jb) invl[jb] = 1.0f / lraw[jb];

#pragma unroll
    for (int chunk = 0; chunk < 4; ++chunk) {
#pragma unroll
      for (int blk = 0; blk < 2; ++blk) {
        int krow = chunk * 32 + 4 * blk + ksel;
        int so = (g ^ swz(krow)) * 8;
        bf16x8 kf0 = *(const bf16x8*)(cur + krow * 32 + so);
        bf16x8 kf1 = *(const bf16x8*)(cur + 4096 + krow * 32 + so);
#pragma unroll
        for (int jb = 0; jb < 2; ++jb) {
          f32x4 s = {};
          s = mfma16(kf0, qf[jb][0], s);
          s = mfma16(kf1, qf[jb][1], s);
#pragma unroll
          for (int r = 0; r < 4; ++r)
            macc[chunk][blk][jb][r] += ex2(s[r] * SC2_) * invl[jb];
        }
      }
    }

    if (h + 1 < H_) {
#pragma unroll
      for (int jb = 0; jb < 2; ++jb) {
#pragma unroll
        for (int ks = 0; ks < 2; ++ks) qf[jb][ks] = qfn[jb][ks];
        lraw[jb] = lrawn[jb];
      }
    }
  }

#pragma unroll
  for (int chunk = 0; chunk < 4; ++chunk)
#pragma unroll
    for (int blk = 0; blk < 2; ++blk)
#pragma unroll
      for (int jb = 0; jb < 2; ++jb) {
        int q = q0 + w * 32 + jb * 16 + l15;
        int kb = k0 + chunk * 32 + 8 * g + 4 * blk;
        f32x4 o;
#pragma unroll
        for (int r = 0; r < 4; ++r) o[r] = macc[chunk][blk][jb][r] * 0.0625f;
        *(f32x4*)(meanout + ((size_t)bI * S_ + q) * S_ + kb) = o;
      }
}

DEVI void gemm_out_body(int id, __bf16* smem,
                        const __bf16* __restrict__ Ctx,
                        const __bf16* __restrict__ Wo,
                        const float* __restrict__ bo,
                        float* __restrict__ out) {
  __bf16* As = smem;          // 4096 elems (8KB)
  __bf16* Bs = smem + 4096;   // 4096 elems (8KB)
  const int m0 = (id & 63) * 128, n0 = (id >> 6) * 128;
  const int t = threadIdx.x, lane = t & 63, w = t >> 6;
  const int wm = w >> 1, wn = w & 1;
  const int l15 = lane & 15, g = lane >> 4;

  f32x4 acc[4][4] = {};

  for (int kk = 0; kk < E_; kk += 32) {
#pragma unroll
    for (int i = 0; i < 2; ++i) {
      int c = t + i * 256;
      int row = c >> 2, kc = c & 3;
      int sl = kc ^ swz(row);
      load_lds16(Ctx + (size_t)(m0 + row) * E_ + kk + sl * 8, (void*)(As + c * 8));
      load_lds16(Wo + (size_t)(n0 + row) * E_ + kk + sl * 8, (void*)(Bs + c * 8));
    }
    __syncthreads();
    bf16x8 a[4], b[4];
#pragma unroll
    for (int i = 0; i < 4; ++i) {
      int row = wm * 64 + i * 16 + l15;
      a[i] = *(const bf16x8*)(As + row * 32 + (g ^ swz(row)) * 8);
    }
#pragma unroll
    for (int j = 0; j < 4; ++j) {
      int row = wn * 64 + j * 16 + l15;
      b[j] = *(const bf16x8*)(Bs + row * 32 + (g ^ swz(row)) * 8);
    }
#pragma unroll
    for (int i = 0; i < 4; ++i)
#pragma unroll
      for (int j = 0; j < 4; ++j)
        acc[i][j] = mfma16(a[i], b[j], acc[i][j]);
    __syncthreads();
  }

#pragma unroll
  for (int i = 0; i < 4; ++i) {
    int mloc = wm * 64 + i * 16 + (g << 2);
#pragma unroll
    for (int j = 0; j < 4; ++j) {
      int n = n0 + wn * 64 + j * 16 + l15;
      float bs = bo[n];
#pragma unroll
      for (int r = 0; r < 4; ++r)
        out[(size_t)(m0 + mloc + r) * E_ + n] = acc[i][j][r] + bs;
    }
  }
}

__global__ __launch_bounds__(256, 3) void tail_fused(const __bf16* __restrict__ Qb,
                                                     const __bf16* __restrict__ Kb,
                                                     const float* __restrict__ Lsum,
                                                     float* __restrict__ meanout,
                                                     const __bf16* __restrict__ Ctx,
                                                     const __bf16* __restrict__ Wo,
                                                     const float* __restrict__ bo,
                                                     float* __restrict__ out) {
  __shared__ __attribute__((aligned(16))) __bf16 smem[16384]; // 32KB, carved per path
  const int bid = blockIdx.x;
  const int g3 = bid / 3, r3 = bid - g3 * 3;  // 2:1 interleave (1024 attn : 512 gemm)
  if (r3 == 2)
    gemm_out_body(g3, smem, Ctx, Wo, bo, out);
  else
    attn_mean_body(2 * g3 + r3, smem, Qb, Kb, Lsum, meanout);
}

extern "C" void kernel_launch(void* const* d_in, const int* in_sizes, int n_in,
                              void* d_out, int out_size, void* d_ws, size_t ws_size,
                              hipStream_t stream) {
  if (ws_size < WS_NEED) {
    hipMemsetAsync(d_out, 0, (size_t)out_size * sizeof(float), stream);
    return;
  }

  const float* q  = (const float*)d_in[0];
  const float* k  = (const float*)d_in[1];
  const float* v  = (const float*)d_in[2];
  const float* Wq = (const float*)d_in[3];
  const float* bq = (const float*)d_in[4];
  const float* Wk = (const float*)d_in[5];
  const float* bk = (const float*)d_in[6];
  const float* Wv = (const float*)d_in[7];
  const float* bv = (const float*)d_in[8];
  const float* Wo = (const float*)d_in[9];
  const float* bo = (const float*)d_in[10];

  char* ws = (char*)d_ws;
  __bf16* Xb  = (__bf16*)(ws + XB_OFF);
  __bf16* Wb  = (__bf16*)(ws + WB_OFF);
  __bf16* Qb  = (__bf16*)(ws + QB_OFF);
  __bf16* Kb  = (__bf16*)(ws + KB_OFF);
  __bf16* Vt  = (__bf16*)(ws + VT_OFF);
  __bf16* Ctx = (__bf16*)(ws + CTX_OFF);
  float*  Ls  = (float*)(ws + LS_OFF);

  float* out0 = (float*)d_out;
  float* out1 = (float*)d_out + (size_t)N_ * E_;

  conv_x<<<dim3(N_ * E_ / 4 / 256, 3), 256, 0, stream>>>(q, k, v, Xb);
  conv_w<<<dim3(E_ * E_ / 4 / 256, 4), 256, 0, stream>>>(Wq, Wk, Wv, Wo, Wb);
  gemm_qkv<<<dim3(N_ / 128, E_ / 128, 3), 256, 0, stream>>>(Xb, Wb, bq, bk, bv, Qb, Kb, Vt);
  attn_pv<<<dim3(S_ / 128, B_ * H_), 256, 0, stream>>>(Qb, Kb, Vt, Ls, Ctx);
  tail_fused<<<dim3(1536), 256, 0, stream>>>(Qb, Kb, Ls, out1, Ctx,
                                             Wb + 3 * (size_t)E_ * E_, bo, out0);
}

// Round 9
// 411.142 us; speedup vs baseline: 1.0396x; 1.0396x over previous
//
#include <hip/hip_runtime.h>
#include <hip/hip_bf16.h>

#define DEVI __device__ __forceinline__

typedef __bf16 bf16x8 __attribute__((ext_vector_type(8)));
typedef __bf16 bf16x4 __attribute__((ext_vector_type(4)));
typedef float f32x4 __attribute__((ext_vector_type(4)));

constexpr int B_ = 4, S_ = 2048, E_ = 1024, H_ = 16, D_ = 64;
constexpr int N_ = B_ * S_;          // 8192 tokens
constexpr float SC2_ = 0.18033688011112042f;  // (1/sqrt(64)) * log2(e) — folded into Qb

// ---- workspace layout (bytes) ----
constexpr size_t XB_OFF = 0;           // bf16 [3][N][E]
constexpr size_t WB_OFF = 50331648;    // bf16 [4][E][E]
constexpr size_t QB_OFF = 58720256;    // bf16 [B][H][S][D]  (pre-scaled by SC2_)
constexpr size_t KB_OFF = 75497472;    // bf16 [B][H][S][D]
constexpr size_t VT_OFF = 92274688;    // bf16 [B][H][D][S]
constexpr size_t CTX_OFF = 109051904;  // bf16 [N][E]
constexpr size_t LS_OFF = 125829120;   // f32  [B][H][S]
constexpr size_t WS_NEED = 126353408;

typedef const __attribute__((address_space(1))) void* gas_ptr;
typedef __attribute__((address_space(3))) void* las_ptr;

DEVI void load_lds16(const void* g, void* l) {
  __builtin_amdgcn_global_load_lds((gas_ptr)g, (las_ptr)l, 16, 0, 0);
}

DEVI f32x4 mfma16(bf16x8 a, bf16x8 b, f32x4 c) {
  return __builtin_amdgcn_mfma_f32_16x16x32_bf16(a, b, c, 0, 0, 0);
}

// xor-swizzle key: 16B slot permutation per row, kills bank-position aliasing
DEVI int swz(int row) { return ((row >> 1) ^ (row >> 3)) & 3; }

#if __has_builtin(__builtin_amdgcn_exp2f)
DEVI float ex2(float x) { return __builtin_amdgcn_exp2f(x); }
#else
DEVI float ex2(float x) { return exp2f(x); }
#endif

// ---------------- conversion fp32 -> bf16 (x and w merged: one launch) ----------------
// flat grid: [0, 24576) -> x part (3 tensors x 8192 blocks), [24576, 28672) -> w part (4 x 1024)
__global__ __launch_bounds__(256) void conv_all(const float* __restrict__ q,
                                                const float* __restrict__ k,
                                                const float* __restrict__ v,
                                                const float* __restrict__ wq,
                                                const float* __restrict__ wk,
                                                const float* __restrict__ wv,
                                                const float* __restrict__ wo,
                                                __bf16* __restrict__ dstx,
                                                __bf16* __restrict__ dstw) {
  const int bid = blockIdx.x;
  const float* src;
  __bf16* d;
  int sub;
  if (bid < 24576) {
    int part = bid >> 13;        // /8192
    sub = bid & 8191;
    src = (part == 0) ? q : ((part == 1) ? k : v);
    d = dstx + (size_t)part * N_ * E_;
  } else {
    int wb = bid - 24576;
    int part = wb >> 10;         // /1024
    sub = wb & 1023;
    src = (part == 0) ? wq : ((part == 1) ? wk : ((part == 2) ? wv : wo));
    d = dstw + (size_t)part * E_ * E_;
  }
  size_t i = ((size_t)sub * blockDim.x + threadIdx.x) * 4;
  float4 f = *(const float4*)(src + i);
  bf16x4 o;
  o[0] = (__bf16)f.x; o[1] = (__bf16)f.y; o[2] = (__bf16)f.z; o[3] = (__bf16)f.w;
  *(bf16x4*)(d + i) = o;
}

// ---------------- fused QKV projection GEMM ----------------
// z==0 (Q): epilogue folds the softmax scale SC2_ into the stored value
// ((acc+bias)*SC2_ in fp32 before the bf16 cast — identical error profile to
// scaling the fp32 scores later, so attn kernels can drop 268M+ muls).
__global__ __launch_bounds__(256) void gemm_qkv(const __bf16* __restrict__ Xb,
                                                const __bf16* __restrict__ Wb,
                                                const float* __restrict__ bq,
                                                const float* __restrict__ bk,
                                                const float* __restrict__ bv,
                                                __bf16* __restrict__ Qb,
                                                __bf16* __restrict__ Kb,
                                                __bf16* __restrict__ Vt) {
  __shared__ __attribute__((aligned(16))) __bf16 As[128 * 32];
  __shared__ __attribute__((aligned(16))) __bf16 Bs[128 * 32];
  const int z = blockIdx.z;
  const __bf16* A = Xb + (size_t)z * N_ * E_;
  const __bf16* W = Wb + (size_t)z * E_ * E_;
  const float* bias = (z == 0) ? bq : ((z == 1) ? bk : bv);
  const int m0 = blockIdx.x * 128, n0 = blockIdx.y * 128;
  const int t = threadIdx.x, lane = t & 63, w = t >> 6;
  const int wm = w >> 1, wn = w & 1;
  const int l15 = lane & 15, g = lane >> 4;

  f32x4 acc[4][4] = {};

  for (int kk = 0; kk < E_; kk += 32) {
#pragma unroll
    for (int i = 0; i < 2; ++i) {
      int c = t + i * 256;
      int row = c >> 2, kc = c & 3;
      int sl = kc ^ swz(row);
      load_lds16(A + (size_t)(m0 + row) * E_ + kk + sl * 8, (void*)(As + c * 8));
      load_lds16(W + (size_t)(n0 + row) * E_ + kk + sl * 8, (void*)(Bs + c * 8));
    }
    __syncthreads();
    bf16x8 a[4], b[4];
#pragma unroll
    for (int i = 0; i < 4; ++i) {
      int row = wm * 64 + i * 16 + l15;
      a[i] = *(const bf16x8*)(As + row * 32 + (g ^ swz(row)) * 8);
    }
#pragma unroll
    for (int j = 0; j < 4; ++j) {
      int row = wn * 64 + j * 16 + l15;
      b[j] = *(const bf16x8*)(Bs + row * 32 + (g ^ swz(row)) * 8);
    }
#pragma unroll
    for (int i = 0; i < 4; ++i)
#pragma unroll
      for (int j = 0; j < 4; ++j)
        acc[i][j] = mfma16(a[i], b[j], acc[i][j]);
    __syncthreads();
  }

  const float oscale = (z == 0) ? SC2_ : 1.0f;
#pragma unroll
  for (int i = 0; i < 4; ++i) {
    int mloc = wm * 64 + i * 16 + (g << 2);
#pragma unroll
    for (int j = 0; j < 4; ++j) {
      int nloc = wn * 64 + j * 16 + l15;
      int n = n0 + nloc;
      int h = n >> 6, d = n & 63;
      float bs = bias[n];
      if (z == 2) {
        int m = m0 + mloc;
        int bb = m >> 11, s = m & 2047;
        bf16x4 pk;
#pragma unroll
        for (int r = 0; r < 4; ++r) pk[r] = (__bf16)(acc[i][j][r] + bs);
        *(bf16x4*)(Vt + ((size_t)(bb * H_ + h) * D_ + d) * S_ + s) = pk;
      } else {
        __bf16* dst = (z == 0) ? Qb : Kb;
#pragma unroll
        for (int r = 0; r < 4; ++r) {
          int m = m0 + mloc + r;
          int bb = m >> 11, s = m & 2047;
          dst[((size_t)(bb * H_ + h) * S_ + s) * D_ + d] = (__bf16)((acc[i][j][r] + bs) * oscale);
        }
      }
    }
  }
}

// ---------------- fused attention via S^T: no P transpose ----------------
// (2-deep counted-vmcnt K/V pipeline; Q pre-scaled -> softmax is ex2(s) directly)
__global__ __launch_bounds__(256, 4) void attn_pv(const __bf16* __restrict__ Qb,
                                                  const __bf16* __restrict__ Kb,
                                                  const __bf16* __restrict__ Vt,
                                                  float* __restrict__ Lsum,
                                                  __bf16* __restrict__ Ctx) {
  // [buf][ Ks 4096 elems | Vs 4096 elems ] = 2 x 16KB
  __shared__ __attribute__((aligned(16))) __bf16 smem[2][8192];

  const int q0 = blockIdx.x * 128;
  const int bh = blockIdx.y;
  const __bf16* Qh = Qb + (size_t)bh * S_ * D_;
  const __bf16* Kh = Kb + (size_t)bh * S_ * D_;
  const __bf16* Vh = Vt + (size_t)bh * D_ * S_;
  const int t = threadIdx.x, lane = t & 63, w = t >> 6;
  const int l15 = lane & 15, g = lane >> 4;
  // interleaved m->k mapping: k_local = 8*(m>>2) + 4*blk + (m&3)
  const int ksel = 8 * (l15 >> 2) + (l15 & 3);

  // Q fragments loaded directly global->VGPR
  bf16x8 qf[2][2]; // [jb][ks]
#pragma unroll
  for (int jb = 0; jb < 2; ++jb) {
    int row = w * 32 + jb * 16 + l15;
#pragma unroll
    for (int ks = 0; ks < 2; ++ks)
      qf[jb][ks] = *(const bf16x8*)(Qh + (size_t)(q0 + row) * D_ + ks * 32 + g * 8);
  }

  bf16x8 ones;
#pragma unroll
  for (int i = 0; i < 8; ++i) ones[i] = (__bf16)1.0f;

  f32x4 acc[4][2] = {};  // [d-block][jb] — O^T tile
  f32x4 lacc[2] = {};    // denominator via ones-MFMA

  // stage one 64-wide K/V tile (4 loads/thread: 2 K + 2 V)
  auto stage_kv = [&](int kk0, __bf16* buf) {
#pragma unroll
    for (int i = 0; i < 2; ++i) {
      int c = t + i * 256;
      int sub = c >> 8, rem = c & 255, row = rem >> 2, kc = rem & 3;
      int sl = kc ^ swz(row);
      load_lds16(Kh + (size_t)(kk0 + row) * D_ + sub * 32 + sl * 8, (void*)(buf + c * 8));
      load_lds16(Vh + (size_t)row * S_ + kk0 + sub * 32 + sl * 8, (void*)(buf + 4096 + c * 8));
    }
  };

  auto compute = [&](const __bf16* Ksb) {
    const __bf16* Vsb = Ksb + 4096;
#pragma unroll
    for (int chunk = 0; chunk < 2; ++chunk) {
      f32x4 sc[2][2]; // [blk][jb]
#pragma unroll
      for (int blk = 0; blk < 2; ++blk) {
        int krow = chunk * 32 + 4 * blk + ksel;
        int so = (g ^ swz(krow)) * 8;
        bf16x8 kf0 = *(const bf16x8*)(Ksb + krow * 32 + so);
        bf16x8 kf1 = *(const bf16x8*)(Ksb + 2048 + krow * 32 + so);
#pragma unroll
        for (int jb = 0; jb < 2; ++jb) {
          f32x4 s = {};
          s = mfma16(kf0, qf[jb][0], s);
          s = mfma16(kf1, qf[jb][1], s);
          sc[blk][jb] = s;
        }
      }
      bf16x8 pf[2];
#pragma unroll
      for (int jb = 0; jb < 2; ++jb) {
#pragma unroll
        for (int r = 0; r < 4; ++r) {
          pf[jb][r]     = (__bf16)ex2(sc[0][jb][r]);
          pf[jb][4 + r] = (__bf16)ex2(sc[1][jb][r]);
        }
        lacc[jb] = mfma16(ones, pf[jb], lacc[jb]);
      }
      __builtin_amdgcn_s_setprio(1);
#pragma unroll
      for (int mb = 0; mb < 4; ++mb) {
        int row = mb * 16 + l15;
        bf16x8 vf = *(const bf16x8*)(Vsb + chunk * 2048 + row * 32 + (g ^ swz(row)) * 8);
#pragma unroll
        for (int jb = 0; jb < 2; ++jb)
          acc[mb][jb] = mfma16(vf, pf[jb], acc[mb][jb]);
      }
      __builtin_amdgcn_s_setprio(0);
    }
  };

  // prologue: fill both buffers (tiles 0 and 1)
  stage_kv(0, smem[0]);
  stage_kv(64, smem[1]);

  for (int tt = 0; tt < 30; ++tt) {
    asm volatile("s_waitcnt vmcnt(4)" ::: "memory");
    __builtin_amdgcn_s_barrier();
    compute(smem[tt & 1]);
    __builtin_amdgcn_s_barrier();             // all waves done reading buf
    stage_kv((tt + 2) * 64, smem[tt & 1]);    // issue-only, no wait
  }
  asm volatile("s_waitcnt vmcnt(4)" ::: "memory");
  __builtin_amdgcn_s_barrier();
  compute(smem[0]);
  asm volatile("s_waitcnt vmcnt(0)" ::: "memory");
  __builtin_amdgcn_s_barrier();
  compute(smem[1]);

  // every lane holds l for its own q column in lacc[jb][0]
  if (lane < 16) {
#pragma unroll
    for (int jb = 0; jb < 2; ++jb)
      Lsum[(size_t)bh * S_ + q0 + w * 32 + jb * 16 + lane] = lacc[jb][0];
  }

  const int bb = bh >> 4, h = bh & 15;
#pragma unroll
  for (int jb = 0; jb < 2; ++jb) {
    float invl = 1.0f / lacc[jb][0];
    int q = q0 + w * 32 + jb * 16 + l15;
#pragma unroll
    for (int mb = 0; mb < 4; ++mb) {
      int d = mb * 16 + (g << 2);
      bf16x4 pk;
#pragma unroll
      for (int r = 0; r < 4; ++r) pk[r] = (__bf16)(acc[mb][jb][r] * invl);
      *(bf16x4*)(Ctx + ((size_t)bb * S_ + q) * E_ + h * 64 + d) = pk;
    }
  }
}

// ---------------- fused tail: attn mean + out-proj GEMM ----------------
// waves=3 (final). Q pre-scaled -> inner triple is {ex2, fma} not {mul, ex2, fma}.

DEVI void attn_mean_body(int id, __bf16* smem,
                         const __bf16* __restrict__ Qb,
                         const __bf16* __restrict__ Kb,
                         const float* __restrict__ Lsum,
                         float* __restrict__ meanout) {
  // smem: two K buffers of 8192 bf16 (16KB each)
  const int k0 = (id & 15) * 128;
  const int q0 = ((id >> 4) & 15) * 128;
  const int bI = id >> 8;
  const int t = threadIdx.x, lane = t & 63, w = t >> 6;
  const int l15 = lane & 15, g = lane >> 4;
  const int ksel = 8 * (l15 >> 2) + (l15 & 3);

  const __bf16* Qbase = Qb + (size_t)bI * H_ * S_ * D_;
  const __bf16* Kbase = Kb + (size_t)bI * H_ * S_ * D_;
  const float* Lbase = Lsum + (size_t)bI * H_ * S_;
  const int qrow0 = q0 + w * 32 + l15;   // jb adds +16

  f32x4 macc[4][2][2] = {}; // [chunk][blk][jb]

  auto stage_k = [&](int h, __bf16* buf) {
    const __bf16* Kh = Kbase + (size_t)h * S_ * D_;
#pragma unroll
    for (int i = 0; i < 4; ++i) {
      int c = t + i * 256;
      int sub = c >> 9, rem = c & 511, row = rem >> 2, kc = rem & 3;
      int sl = kc ^ swz(row);
      load_lds16(Kh + (size_t)(k0 + row) * D_ + sub * 32 + sl * 8, (void*)(buf + c * 8));
    }
  };

  // prologue: stage K[0], prefetch q/l for head 0
  stage_k(0, smem);
  bf16x8 qf[2][2];
  float lraw[2];
#pragma unroll
  for (int jb = 0; jb < 2; ++jb) {
#pragma unroll
    for (int ks = 0; ks < 2; ++ks)
      qf[jb][ks] = *(const bf16x8*)(Qbase + (size_t)(qrow0 + jb * 16) * D_ + ks * 32 + g * 8);
    lraw[jb] = Lbase[qrow0 + jb * 16];
  }

  for (int h = 0; h < H_; ++h) {   // rolled: avoid 16x code bloat / live-range blowup
    __bf16* cur = (h & 1) ? (smem + 8192) : smem;
    __bf16* nxt = (h & 1) ? smem : (smem + 8192);

    // everything issued during head h-1 (K[h] stage, qf, lraw) is >=1 full
    // compute phase old -> this drain is near-free
    asm volatile("s_waitcnt vmcnt(0)" ::: "memory");
    __builtin_amdgcn_s_barrier();

    // prefetch next head's operands; in flight across this compute phase
    bf16x8 qfn[2][2];
    float lrawn[2];
    if (h + 1 < H_) {
      const __bf16* Qn = Qbase + (size_t)(h + 1) * S_ * D_;
#pragma unroll
      for (int jb = 0; jb < 2; ++jb) {
#pragma unroll
        for (int ks = 0; ks < 2; ++ks)
          qfn[jb][ks] = *(const bf16x8*)(Qn + (size_t)(qrow0 + jb * 16) * D_ + ks * 32 + g * 8);
        lrawn[jb] = Lbase[(size_t)(h + 1) * S_ + qrow0 + jb * 16];
      }
      stage_k(h + 1, nxt);
    }
    __builtin_amdgcn_sched_barrier(0);  // pin: prefetch issued before compute

    float invl[2];
#pragma unroll
    for (int jb = 0; jb < 2; ++jb) invl[jb] = 1.0f / lraw[jb];

#pragma unroll
    for (int chunk = 0; chunk < 4; ++chunk) {
#pragma unroll
      for (int blk = 0; blk < 2; ++blk) {
        int krow = chunk * 32 + 4 * blk + ksel;
        int so = (g ^ swz(krow)) * 8;
        bf16x8 kf0 = *(const bf16x8*)(cur + krow * 32 + so);
        bf16x8 kf1 = *(const bf16x8*)(cur + 4096 + krow * 32 + so);
#pragma unroll
        for (int jb = 0; jb < 2; ++jb) {
          f32x4 s = {};
          s = mfma16(kf0, qf[jb][0], s);
          s = mfma16(kf1, qf[jb][1], s);
#pragma unroll
          for (int r = 0; r < 4; ++r)
            macc[chunk][blk][jb][r] += ex2(s[r]) * invl[jb];
        }
      }
    }

    if (h + 1 < H_) {
#pragma unroll
      for (int jb = 0; jb < 2; ++jb) {
#pragma unroll
        for (int ks = 0; ks < 2; ++ks) qf[jb][ks] = qfn[jb][ks];
        lraw[jb] = lrawn[jb];
      }
    }
  }

#pragma unroll
  for (int chunk = 0; chunk < 4; ++chunk)
#pragma unroll
    for (int blk = 0; blk < 2; ++blk)
#pragma unroll
      for (int jb = 0; jb < 2; ++jb) {
        int q = q0 + w * 32 + jb * 16 + l15;
        int kb = k0 + chunk * 32 + 8 * g + 4 * blk;
        f32x4 o;
#pragma unroll
        for (int r = 0; r < 4; ++r) o[r] = macc[chunk][blk][jb][r] * 0.0625f;
        *(f32x4*)(meanout + ((size_t)bI * S_ + q) * S_ + kb) = o;
      }
}

DEVI void gemm_out_body(int id, __bf16* smem,
                        const __bf16* __restrict__ Ctx,
                        const __bf16* __restrict__ Wo,
                        const float* __restrict__ bo,
                        float* __restrict__ out) {
  __bf16* As = smem;          // 4096 elems (8KB)
  __bf16* Bs = smem + 4096;   // 4096 elems (8KB)
  const int m0 = (id & 63) * 128, n0 = (id >> 6) * 128;
  const int t = threadIdx.x, lane = t & 63, w = t >> 6;
  const int wm = w >> 1, wn = w & 1;
  const int l15 = lane & 15, g = lane >> 4;

  f32x4 acc[4][4] = {};

  for (int kk = 0; kk < E_; kk += 32) {
#pragma unroll
    for (int i = 0; i < 2; ++i) {
      int c = t + i * 256;
      int row = c >> 2, kc = c & 3;
      int sl = kc ^ swz(row);
      load_lds16(Ctx + (size_t)(m0 + row) * E_ + kk + sl * 8, (void*)(As + c * 8));
      load_lds16(Wo + (size_t)(n0 + row) * E_ + kk + sl * 8, (void*)(Bs + c * 8));
    }
    __syncthreads();
    bf16x8 a[4], b[4];
#pragma unroll
    for (int i = 0; i < 4; ++i) {
      int row = wm * 64 + i * 16 + l15;
      a[i] = *(const bf16x8*)(As + row * 32 + (g ^ swz(row)) * 8);
    }
#pragma unroll
    for (int j = 0; j < 4; ++j) {
      int row = wn * 64 + j * 16 + l15;
      b[j] = *(const bf16x8*)(Bs + row * 32 + (g ^ swz(row)) * 8);
    }
#pragma unroll
    for (int i = 0; i < 4; ++i)
#pragma unroll
      for (int j = 0; j < 4; ++j)
        acc[i][j] = mfma16(a[i], b[j], acc[i][j]);
    __syncthreads();
  }

#pragma unroll
  for (int i = 0; i < 4; ++i) {
    int mloc = wm * 64 + i * 16 + (g << 2);
#pragma unroll
    for (int j = 0; j < 4; ++j) {
      int n = n0 + wn * 64 + j * 16 + l15;
      float bs = bo[n];
#pragma unroll
      for (int r = 0; r < 4; ++r)
        out[(size_t)(m0 + mloc + r) * E_ + n] = acc[i][j][r] + bs;
    }
  }
}

__global__ __launch_bounds__(256, 3) void tail_fused(const __bf16* __restrict__ Qb,
                                                     const __bf16* __restrict__ Kb,
                                                     const float* __restrict__ Lsum,
                                                     float* __restrict__ meanout,
                                                     const __bf16* __restrict__ Ctx,
                                                     const __bf16* __restrict__ Wo,
                                                     const float* __restrict__ bo,
                                                     float* __restrict__ out) {
  __shared__ __attribute__((aligned(16))) __bf16 smem[16384]; // 32KB, carved per path
  const int bid = blockIdx.x;
  const int g3 = bid / 3, r3 = bid - g3 * 3;  // 2:1 interleave (1024 attn : 512 gemm)
  if (r3 == 2)
    gemm_out_body(g3, smem, Ctx, Wo, bo, out);
  else
    attn_mean_body(2 * g3 + r3, smem, Qb, Kb, Lsum, meanout);
}

extern "C" void kernel_launch(void* const* d_in, const int* in_sizes, int n_in,
                              void* d_out, int out_size, void* d_ws, size_t ws_size,
                              hipStream_t stream) {
  if (ws_size < WS_NEED) {
    hipMemsetAsync(d_out, 0, (size_t)out_size * sizeof(float), stream);
    return;
  }

  const float* q  = (const float*)d_in[0];
  const float* k  = (const float*)d_in[1];
  const float* v  = (const float*)d_in[2];
  const float* Wq = (const float*)d_in[3];
  const float* bq = (const float*)d_in[4];
  const float* Wk = (const float*)d_in[5];
  const float* bk = (const float*)d_in[6];
  const float* Wv = (const float*)d_in[7];
  const float* bv = (const float*)d_in[8];
  const float* Wo = (const float*)d_in[9];
  const float* bo = (const float*)d_in[10];

  char* ws = (char*)d_ws;
  __bf16* Xb  = (__bf16*)(ws + XB_OFF);
  __bf16* Wb  = (__bf16*)(ws + WB_OFF);
  __bf16* Qb  = (__bf16*)(ws + QB_OFF);
  __bf16* Kb  = (__bf16*)(ws + KB_OFF);
  __bf16* Vt  = (__bf16*)(ws + VT_OFF);
  __bf16* Ctx = (__bf16*)(ws + CTX_OFF);
  float*  Ls  = (float*)(ws + LS_OFF);

  float* out0 = (float*)d_out;
  float* out1 = (float*)d_out + (size_t)N_ * E_;

  conv_all<<<dim3(28672), 256, 0, stream>>>(q, k, v, Wq, Wk, Wv, Wo, Xb, Wb);
  gemm_qkv<<<dim3(N_ / 128, E_ / 128, 3), 256, 0, stream>>>(Xb, Wb, bq, bk, bv, Qb, Kb, Vt);
  attn_pv<<<dim3(S_ / 128, B_ * H_), 256, 0, stream>>>(Qb, Kb, Vt, Ls, Ctx);
  tail_fused<<<dim3(1536), 256, 0, stream>>>(Qb, Kb, Ls, out1, Ctx,
                                             Wb + 3 * (size_t)E_ * E_, bo, out0);
}